// Round 4
// baseline (1296.554 us; speedup 1.0000x reference)
//
#include <hip/hip_runtime.h>
#include <hip/hip_bf16.h>

typedef unsigned short u16;
typedef __bf16 bf16x8v __attribute__((ext_vector_type(8)));
typedef float f32x4v __attribute__((ext_vector_type(4)));

// ---------- bf16 helpers (RNE) ----------
__device__ __forceinline__ float bf2f(u16 u) {
    union { float f; unsigned int i; } c; c.i = ((unsigned int)u) << 16; return c.f;
}
__device__ __forceinline__ u16 f2bf(float f) {
    union { float f; unsigned int i; } c; c.f = f;
    unsigned int i = c.i;
    unsigned int lsb = (i >> 16) & 1u;
    i += 0x7fffu + lsb;
    return (u16)(i >> 16);
}
__device__ __forceinline__ float lo16(unsigned u) { return bf2f((u16)(u & 0xffff)); }
__device__ __forceinline__ float hi16(unsigned u) { return bf2f((u16)(u >> 16)); }
__device__ __forceinline__ unsigned pack2(float lo, float hi) {
    return (unsigned)f2bf(lo) | ((unsigned)f2bf(hi) << 16);
}

// ---------- weight packing: Wt[n][k] = W[k][n], K padded with zeros ----------
__global__ void pack_w(const float* __restrict__ W, u16* __restrict__ Wt, int K, int Kpad) {
    int idx = blockIdx.x * 256 + threadIdx.x;
    if (idx >= 256 * Kpad) return;
    int n = idx / Kpad, k = idx % Kpad;
    float v = (k < K) ? W[k * 256 + n] : 0.f;
    Wt[idx] = f2bf(v);
}

// W_o packed for reordered concat: a_input = [a_message(256) | f_atoms(133) | pad(to 448)]
__global__ void pack_wo(const float* __restrict__ W_o, u16* __restrict__ Wt) {
    int idx = blockIdx.x * 256 + threadIdx.x;
    if (idx >= 256 * 448) return;
    int n = idx / 448, k = idx % 448;
    float v;
    if (k < 256)       v = W_o[(133 + k) * 256 + n];
    else if (k < 389)  v = W_o[(k - 256) * 256 + n];
    else               v = 0.f;
    Wt[idx] = f2bf(v);
}

// ---------- f_bonds fp32[nB][147] -> bf16[nB][192] zero-padded ----------
__global__ void convert_fbonds(const float* __restrict__ fb, u16* __restrict__ out, int nB) {
    int idx = blockIdx.x * 256 + threadIdx.x;
    if (idx >= nB * 192) return;
    int b = idx / 192, k = idx % 192;
    float v = (k < 147) ? fb[b * 147 + k] : 0.f;
    out[idx] = f2bf(v);
}

// ---------- f_atoms fp32[nA][133] -> bf16[nA][192] zero-padded ----------
__global__ void convert_fatoms(const float* __restrict__ fa, u16* __restrict__ out, int nA) {
    int idx = blockIdx.x * 256 + threadIdx.x;
    if (idx >= nA * 192) return;
    int a = idx / 192, c = idx % 192;
    float v = (c < 133) ? fa[a * 133 + c] : 0.f;
    out[idx] = f2bf(v);
}

// ---------- gather: amsg[a][h] = sum_j relu?(msg[a2b[a][j]][h]) * w_bonds[a2b[a][j]] ----------
template <bool RELU>
__global__ __launch_bounds__(256)
void gather_kernel(const u16* __restrict__ msg, const int* __restrict__ a2b,
                   const float* __restrict__ w_bonds, u16* __restrict__ out,
                   int nAtoms) {
    int t = threadIdx.x;
    int atom = blockIdx.x * 4 + (t >> 6);
    int lane = t & 63;
    if (atom >= nAtoms) return;
    float a0 = 0.f, a1 = 0.f, a2 = 0.f, a3 = 0.f;
#pragma unroll
    for (int j = 0; j < 6; ++j) {
        int b = a2b[atom * 6 + j];
        float w = w_bonds[b];
        uint2 v = *(const uint2*)(msg + (size_t)b * 256 + lane * 4);
        float m0 = lo16(v.x), m1 = hi16(v.x), m2 = lo16(v.y), m3 = hi16(v.y);
        if (RELU) { m0 = fmaxf(m0, 0.f); m1 = fmaxf(m1, 0.f); m2 = fmaxf(m2, 0.f); m3 = fmaxf(m3, 0.f); }
        a0 += w * m0; a1 += w * m1; a2 += w * m2; a3 += w * m3;
    }
    uint2 o;
    o.x = pack2(a0, a1);
    o.y = pack2(a2, a3);
    *(uint2*)(out + (size_t)atom * 256 + lane * 4) = o;
}

// ---------- streaming GEMM (contiguous A, optionally split into two matrices) ----------
// C[M][256] cols [blockIdx.y*64, +64) = A[M][KPAD] @ Bt[256][KPAD]^T
// A cols [0,KSPLIT) from A1 (row stride KSPLIT); cols [KSPLIT,KPAD) from A2 (row stride KPAD-KSPLIT).
// Weight slice in LDS (staged once, row pad +8 elems -> 2-way aliasing only). No barriers in loop.
// MODE 0: out0 = bf16(acc).  MODE 2: outf = relu(acc + bias[col]) fp32.
template <int MODE, int KPAD, int KSPLIT, int NT>
__global__ __launch_bounds__(256, 3)
void gemm_stream(const u16* __restrict__ A1, const u16* __restrict__ A2,
                 const u16* __restrict__ Bt, int M,
                 const float* __restrict__ bias,
                 u16* __restrict__ out0, float* __restrict__ outf) {
    constexpr int LSTR = KPAD + 8;
    constexpr int NROWS = NT * 16;
    constexpr int K2 = KPAD - KSPLIT;
    __shared__ u16 Bs[NROWS * LSTR];
    const int tid = threadIdx.x;
    const int wave = tid >> 6;
    const int lane = tid & 63;
    const int mrow = lane & 15;
    const int quad = lane >> 4;
    const int nbase = blockIdx.y * NROWS;

    constexpr int KC = KPAD / 8;
    for (int i = tid; i < NROWS * KC; i += 256) {
        int r = i / KC, kc = i % KC;
        *(uint4*)&Bs[r * LSTR + kc * 8] =
            *(const uint4*)&Bt[(size_t)(nbase + r) * KPAD + kc * 8];
    }
    __syncthreads();

    for (long chunk = blockIdx.x; chunk * 256 < (long)M; chunk += gridDim.x) {
        const long mbase = chunk * 256 + wave * 64;
        long row[4];
#pragma unroll
        for (int t = 0; t < 4; ++t) {
            long r = mbase + t * 16 + mrow;
            if (r >= M) r = M - 1;
            row[t] = r;
        }

        f32x4v acc[4][NT];
#pragma unroll
        for (int t = 0; t < 4; ++t)
#pragma unroll
            for (int j = 0; j < NT; ++j) acc[t][j] = (f32x4v){0.f, 0.f, 0.f, 0.f};

#pragma unroll 2
        for (int k0 = 0; k0 < KSPLIT; k0 += 32) {
            bf16x8v a_frag[4], b_frag[NT];
#pragma unroll
            for (int t = 0; t < 4; ++t)
                a_frag[t] = *(const bf16x8v*)&A1[row[t] * KSPLIT + k0 + quad * 8];
#pragma unroll
            for (int j = 0; j < NT; ++j)
                b_frag[j] = *(const bf16x8v*)&Bs[(j * 16 + mrow) * LSTR + k0 + quad * 8];
#pragma unroll
            for (int t = 0; t < 4; ++t)
#pragma unroll
                for (int j = 0; j < NT; ++j)
                    acc[t][j] = __builtin_amdgcn_mfma_f32_16x16x32_bf16(
                        a_frag[t], b_frag[j], acc[t][j], 0, 0, 0);
        }
        if constexpr (K2 > 0) {
#pragma unroll 2
            for (int k0 = 0; k0 < K2; k0 += 32) {
                bf16x8v a_frag[4], b_frag[NT];
#pragma unroll
                for (int t = 0; t < 4; ++t)
                    a_frag[t] = *(const bf16x8v*)&A2[row[t] * K2 + k0 + quad * 8];
#pragma unroll
                for (int j = 0; j < NT; ++j)
                    b_frag[j] = *(const bf16x8v*)&Bs[(j * 16 + mrow) * LSTR + KSPLIT + k0 + quad * 8];
#pragma unroll
                for (int t = 0; t < 4; ++t)
#pragma unroll
                    for (int j = 0; j < NT; ++j)
                        acc[t][j] = __builtin_amdgcn_mfma_f32_16x16x32_bf16(
                            a_frag[t], b_frag[j], acc[t][j], 0, 0, 0);
            }
        }

        // epilogue: C/D layout col=lane&15, row=quad*4+reg
#pragma unroll
        for (int t = 0; t < 4; ++t) {
#pragma unroll
            for (int r = 0; r < 4; ++r) {
                long grow = mbase + t * 16 + quad * 4 + r;
                if (grow < M) {
#pragma unroll
                    for (int j = 0; j < NT; ++j) {
                        int gcol = nbase + j * 16 + mrow;
                        size_t idx = (size_t)grow * 256 + gcol;
                        float v = acc[t][j][r];
                        if constexpr (MODE == 0) {
                            out0[idx] = f2bf(v);
                        } else {
                            float s = v + bias[gcol];
                            outf[idx] = s > 0.f ? s : 0.f;
                        }
                    }
                }
            }
        }
    }
}

// ---------- fused message GEMM ----------
// msg_new[b][cols] = relu( inp[b] + (amsg[b2a[b]] - relu?(msgsrc[b2revb[b]])) @ Wh^T )
// A-fragments computed on the fly from gathered 16B loads (quad-contiguous, L3-resident).
template <bool RELUV>
__global__ __launch_bounds__(256, 3)
void gemm_fused(const u16* __restrict__ amsg, const u16* __restrict__ msgsrc,
                const int* __restrict__ b2a, const int* __restrict__ b2revb,
                const u16* __restrict__ Bt, int M,
                const u16* __restrict__ inp, u16* __restrict__ out0) {
    constexpr int KPAD = 256, NT = 4;
    constexpr int LSTR = KPAD + 8;
    constexpr int NROWS = NT * 16;
    __shared__ u16 Bs[NROWS * LSTR];
    const int tid = threadIdx.x;
    const int wave = tid >> 6;
    const int lane = tid & 63;
    const int mrow = lane & 15;
    const int quad = lane >> 4;
    const int nbase = blockIdx.y * NROWS;

    constexpr int KC = KPAD / 8;
    for (int i = tid; i < NROWS * KC; i += 256) {
        int r = i / KC, kc = i % KC;
        *(uint4*)&Bs[r * LSTR + kc * 8] =
            *(const uint4*)&Bt[(size_t)(nbase + r) * KPAD + kc * 8];
    }
    __syncthreads();

    for (long chunk = blockIdx.x; chunk * 256 < (long)M; chunk += gridDim.x) {
        const long mbase = chunk * 256 + wave * 64;
        size_t soff[4], roff[4];
#pragma unroll
        for (int t = 0; t < 4; ++t) {
            long b = mbase + t * 16 + mrow;
            if (b >= M) b = M - 1;
            soff[t] = (size_t)b2a[b] * 256 + quad * 8;
            roff[t] = (size_t)b2revb[b] * 256 + quad * 8;
        }

        f32x4v acc[4][NT];
#pragma unroll
        for (int t = 0; t < 4; ++t)
#pragma unroll
            for (int j = 0; j < NT; ++j) acc[t][j] = (f32x4v){0.f, 0.f, 0.f, 0.f};

#pragma unroll 2
        for (int k0 = 0; k0 < KPAD; k0 += 32) {
            bf16x8v a_frag[4], b_frag[NT];
#pragma unroll
            for (int t = 0; t < 4; ++t) {
                uint4 va = *(const uint4*)&amsg[soff[t] + k0];
                uint4 vr = *(const uint4*)&msgsrc[roff[t] + k0];
                unsigned pa[4] = {va.x, va.y, va.z, va.w};
                unsigned pr[4] = {vr.x, vr.y, vr.z, vr.w};
                union { unsigned u[4]; bf16x8v v; } res;
#pragma unroll
                for (int p = 0; p < 4; ++p) {
                    float rl = lo16(pr[p]), rh = hi16(pr[p]);
                    if (RELUV) { rl = fmaxf(rl, 0.f); rh = fmaxf(rh, 0.f); }
                    res.u[p] = pack2(lo16(pa[p]) - rl, hi16(pa[p]) - rh);
                }
                a_frag[t] = res.v;
            }
#pragma unroll
            for (int j = 0; j < NT; ++j)
                b_frag[j] = *(const bf16x8v*)&Bs[(j * 16 + mrow) * LSTR + k0 + quad * 8];
#pragma unroll
            for (int t = 0; t < 4; ++t)
#pragma unroll
                for (int j = 0; j < NT; ++j)
                    acc[t][j] = __builtin_amdgcn_mfma_f32_16x16x32_bf16(
                        a_frag[t], b_frag[j], acc[t][j], 0, 0, 0);
        }

        // epilogue: msg_new = relu(inp + acc)
#pragma unroll
        for (int t = 0; t < 4; ++t) {
#pragma unroll
            for (int r = 0; r < 4; ++r) {
                long grow = mbase + t * 16 + quad * 4 + r;
                if (grow < M) {
#pragma unroll
                    for (int j = 0; j < NT; ++j) {
                        int gcol = nbase + j * 16 + mrow;
                        size_t idx = (size_t)grow * 256 + gcol;
                        float s = bf2f(inp[idx]) + acc[t][j][r];
                        out0[idx] = f2bf(s > 0.f ? s : 0.f);
                    }
                }
            }
        }
    }
}

// ---------- per-molecule weighted mean (mol_ids sorted) ----------
__global__ __launch_bounds__(256)
void aggregate_kernel(const float* __restrict__ hid, const float* __restrict__ w_atoms,
                      const int* __restrict__ mol_ids, const float* __restrict__ deg,
                      float* __restrict__ out, int nAtoms) {
    int m = blockIdx.x;
    int t = threadIdx.x;
    int lo = 0, hi = nAtoms;
    while (lo < hi) { int mid = (lo + hi) >> 1; if (mol_ids[mid] < m) lo = mid + 1; else hi = mid; }
    int start = lo;
    lo = start; hi = nAtoms;
    while (lo < hi) { int mid = (lo + hi) >> 1; if (mol_ids[mid] < m + 1) lo = mid + 1; else hi = mid; }
    int end = lo;
    float acc = 0.f, wsum = 0.f;
    for (int a = start; a < end; ++a) {
        float w = w_atoms[a];
        wsum += w;
        acc += w * hid[(size_t)a * 256 + t];
    }
    float res = (wsum > 0.f) ? deg[m] * acc / wsum : 0.f;
    out[m * 256 + t] = res;
}

// ---------- launch ----------
extern "C" void kernel_launch(void* const* d_in, const int* in_sizes, int n_in,
                              void* d_out, int out_size, void* d_ws, size_t ws_size,
                              hipStream_t stream) {
    const float* f_atoms = (const float*)d_in[0];
    const float* f_bonds = (const float*)d_in[1];
    const float* w_atoms = (const float*)d_in[2];
    const float* w_bonds = (const float*)d_in[3];
    const float* W_i     = (const float*)d_in[4];
    const float* W_h     = (const float*)d_in[5];
    const float* W_o     = (const float*)d_in[6];
    const float* b_o     = (const float*)d_in[7];
    const float* deg     = (const float*)d_in[8];
    const int*   a2b     = (const int*)d_in[9];
    const int*   b2a     = (const int*)d_in[10];
    const int*   b2revb  = (const int*)d_in[11];
    const int*   mol_ids = (const int*)d_in[12];
    float* out = (float*)d_out;

    const int nB = 250000, nA = 100000, nM = 2000;

    // ws layout (bytes):
    //  P0 @ 0     : inp bf16 [250k][256] = 128 MB  (later: hid fp32 [100k][256] = 102.4 MB)
    //  P1 @ 128M  : msgA bf16 [250k][256] = 128 MB (later: fatoms_bf [100k][192] = 38.4 MB)
    //  P2 @ 256M  : fbonds_bf [250k][192] = 96 MB  (later: msgB bf16 [250k][256] = 128 MB)
    //  P3 @ 384M  : amsg bf16 [100k][256] = 51.2 MB
    //  P4 @ 435.2M: Wt_i (98,304) | Wt_h (131,072) | Wt_o (229,376)
    char* ws = (char*)d_ws;
    u16* inp    = (u16*)(ws);
    u16* msgA   = (u16*)(ws + 128000000L);
    u16* buf2   = (u16*)(ws + 256000000L);     // fbonds_bf then msgB
    u16* amsg   = (u16*)(ws + 384000000L);
    u16* wt_i   = (u16*)(ws + 435200000L);
    u16* wt_h   = (u16*)(ws + 435200000L + 98304L);
    u16* wt_o   = (u16*)(ws + 435200000L + 98304L + 131072L);
    u16* fatoms = msgA;                         // reuse P1 after msgA dead
    float* hid  = (float*)(ws);                 // reuse P0 after inp dead

    if (ws_size < 435658752UL) return;

    dim3 blk(256);
    pack_w<<<dim3((256 * 192 + 255) / 256), blk, 0, stream>>>(W_i, wt_i, 147, 192);
    pack_w<<<dim3((256 * 256 + 255) / 256), blk, 0, stream>>>(W_h, wt_h, 256, 256);
    pack_wo<<<dim3((256 * 448 + 255) / 256), blk, 0, stream>>>(W_o, wt_o);
    convert_fbonds<<<dim3(nB * 192 / 256), blk, 0, stream>>>(f_bonds, buf2, nB);

    // GEMM1: inp = fbonds_bf @ W_i^T
    gemm_stream<0, 192, 192, 4><<<dim3(256, 4), blk, 0, stream>>>(
        buf2, buf2, wt_i, nB, nullptr, inp, nullptr);

    // iteration 0 (msg == relu(inp) applied on the fly)
    gather_kernel<true><<<dim3(nA / 4), blk, 0, stream>>>(inp, a2b, w_bonds, amsg, nA);
    gemm_fused<true><<<dim3(256, 4), blk, 0, stream>>>(
        amsg, inp, b2a, b2revb, wt_h, nB, inp, msgA);

    // iteration 1
    gather_kernel<false><<<dim3(nA / 4), blk, 0, stream>>>(msgA, a2b, w_bonds, amsg, nA);
    gemm_fused<false><<<dim3(256, 4), blk, 0, stream>>>(
        amsg, msgA, b2a, b2revb, wt_h, nB, inp, buf2 /*msgB*/);

    // final readout
    convert_fatoms<<<dim3(nA * 192 / 256), blk, 0, stream>>>(f_atoms, fatoms, nA);
    gather_kernel<false><<<dim3(nA / 4), blk, 0, stream>>>(buf2 /*msgB*/, a2b, w_bonds, amsg, nA);
    gemm_stream<2, 448, 256, 4><<<dim3(128, 4), blk, 0, stream>>>(
        amsg, fatoms, wt_o, nA, b_o, nullptr, hid);

    aggregate_kernel<<<dim3(nM), blk, 0, stream>>>(hid, w_atoms, mol_ids, deg, out, nA);
}

// Round 5
// 1006.251 us; speedup vs baseline: 1.2885x; 1.2885x over previous
//
#include <hip/hip_runtime.h>
#include <hip/hip_bf16.h>

typedef unsigned short u16;
typedef __bf16 bf16x8v __attribute__((ext_vector_type(8)));
typedef float f32x4v __attribute__((ext_vector_type(4)));

// ---------- bf16 helpers (RNE) ----------
__device__ __forceinline__ float bf2f(u16 u) {
    union { float f; unsigned int i; } c; c.i = ((unsigned int)u) << 16; return c.f;
}
__device__ __forceinline__ u16 f2bf(float f) {
    union { float f; unsigned int i; } c; c.f = f;
    unsigned int i = c.i;
    unsigned int lsb = (i >> 16) & 1u;
    i += 0x7fffu + lsb;
    return (u16)(i >> 16);
}
__device__ __forceinline__ float lo16(unsigned u) { return bf2f((u16)(u & 0xffff)); }
__device__ __forceinline__ float hi16(unsigned u) { return bf2f((u16)(u >> 16)); }
__device__ __forceinline__ unsigned pack2(float lo, float hi) {
    return (unsigned)f2bf(lo) | ((unsigned)f2bf(hi) << 16);
}

// ---------- weight packing: Wt[n][k] = W[k][n], K padded with zeros ----------
__global__ void pack_w(const float* __restrict__ W, u16* __restrict__ Wt, int K, int Kpad) {
    int idx = blockIdx.x * 256 + threadIdx.x;
    if (idx >= 256 * Kpad) return;
    int n = idx / Kpad, k = idx % Kpad;
    float v = (k < K) ? W[k * 256 + n] : 0.f;
    Wt[idx] = f2bf(v);
}

// W_o packed for reordered concat: a_input = [a_message(256) | f_atoms(133) | pad(to 448)]
__global__ void pack_wo(const float* __restrict__ W_o, u16* __restrict__ Wt) {
    int idx = blockIdx.x * 256 + threadIdx.x;
    if (idx >= 256 * 448) return;
    int n = idx / 448, k = idx % 448;
    float v;
    if (k < 256)       v = W_o[(133 + k) * 256 + n];
    else if (k < 389)  v = W_o[(k - 256) * 256 + n];
    else               v = 0.f;
    Wt[idx] = f2bf(v);
}

// ---------- f_bonds fp32[nB][147] -> bf16[nB][192] zero-padded ----------
__global__ void convert_fbonds(const float* __restrict__ fb, u16* __restrict__ out, int nB) {
    int idx = blockIdx.x * 256 + threadIdx.x;
    if (idx >= nB * 192) return;
    int b = idx / 192, k = idx % 192;
    float v = (k < 147) ? fb[b * 147 + k] : 0.f;
    out[idx] = f2bf(v);
}

// ---------- f_atoms fp32[nA][133] -> bf16[nA][192] zero-padded ----------
__global__ void convert_fatoms(const float* __restrict__ fa, u16* __restrict__ out, int nA) {
    int idx = blockIdx.x * 256 + threadIdx.x;
    if (idx >= nA * 192) return;
    int a = idx / 192, c = idx % 192;
    float v = (c < 133) ? fa[a * 133 + c] : 0.f;
    out[idx] = f2bf(v);
}

// ---------- gather (16B/lane): amsg[a][h] = sum_j relu?(msg[a2b[a][j]][h]) * w_bonds[...] ----------
// 32 lanes per atom (8 cols each), 8 atoms per 256-thread block.
template <bool RELU>
__global__ __launch_bounds__(256)
void gather16(const u16* __restrict__ msg, const int* __restrict__ a2b,
              const float* __restrict__ w_bonds, u16* __restrict__ out, int nAtoms) {
    int t = threadIdx.x;
    int atom = blockIdx.x * 8 + (t >> 5);
    int co = (t & 31) * 8;                 // column offset (8 cols = 16 B)
    if (atom >= nAtoms) return;
    float a[8] = {0.f, 0.f, 0.f, 0.f, 0.f, 0.f, 0.f, 0.f};
#pragma unroll
    for (int j = 0; j < 6; ++j) {
        int b = a2b[atom * 6 + j];
        float w = w_bonds[b];
        uint4 v = *(const uint4*)(msg + (size_t)b * 256 + co);
        unsigned p[4] = {v.x, v.y, v.z, v.w};
#pragma unroll
        for (int q = 0; q < 4; ++q) {
            float m0 = lo16(p[q]), m1 = hi16(p[q]);
            if (RELU) { m0 = fmaxf(m0, 0.f); m1 = fmaxf(m1, 0.f); }
            a[q * 2]     += w * m0;
            a[q * 2 + 1] += w * m1;
        }
    }
    uint4 o;
    o.x = pack2(a[0], a[1]); o.y = pack2(a[2], a[3]);
    o.z = pack2(a[4], a[5]); o.w = pack2(a[6], a[7]);
    *(uint4*)(out + (size_t)atom * 256 + co) = o;
}

// ---------- directed message (16B/lane): mdir[b] = amsg[b2a[b]] - relu?(msg[b2revb[b]]) ----------
template <bool RELU>
__global__ __launch_bounds__(256)
void direct16(const u16* __restrict__ amsg, const u16* __restrict__ msg,
              const int* __restrict__ b2a, const int* __restrict__ b2revb,
              u16* __restrict__ mdir, int nBonds) {
    int t = threadIdx.x;
    int bond = blockIdx.x * 8 + (t >> 5);
    int co = (t & 31) * 8;
    if (bond >= nBonds) return;
    int sa = b2a[bond], rb = b2revb[bond];
    uint4 va = *(const uint4*)(amsg + (size_t)sa * 256 + co);
    uint4 vr = *(const uint4*)(msg + (size_t)rb * 256 + co);
    unsigned pa[4] = {va.x, va.y, va.z, va.w};
    unsigned pr[4] = {vr.x, vr.y, vr.z, vr.w};
    uint4 o;
    unsigned po[4];
#pragma unroll
    for (int q = 0; q < 4; ++q) {
        float rl = lo16(pr[q]), rh = hi16(pr[q]);
        if (RELU) { rl = fmaxf(rl, 0.f); rh = fmaxf(rh, 0.f); }
        po[q] = pack2(lo16(pa[q]) - rl, hi16(pa[q]) - rh);
    }
    o.x = po[0]; o.y = po[1]; o.z = po[2]; o.w = po[3];
    *(uint4*)(mdir + (size_t)bond * 256 + co) = o;
}

// ---------- single-pass full-N streaming GEMM ----------
// C[M][256] = A[M][KPAD] @ Bt[256][KPAD]^T, full weight resident in LDS (one stage, one barrier).
// Block = 512 threads (8 waves), wave tile = 32 rows x 256 cols (2 m-tiles x 16 n-tiles),
// acc = 128 AGPR/lane. A streamed global->register (16B/lane), read EXACTLY ONCE per GEMM.
// No barriers in the k-loop. Grid-stride over 256-row chunks.
// MODE 0: out0 = bf16(acc).  MODE 1: out0 = bf16(relu(bf2f(inp)+acc)) (out0 may alias inp).
template <int MODE, int KPAD>
__global__ __launch_bounds__(512, 2)
void gemm_full(const u16* __restrict__ A, const u16* __restrict__ Bt, int M,
               const u16* __restrict__ inp, u16* __restrict__ out0) {
    constexpr int LSTR = KPAD + 8;          // keeps 16B row alignment (+16B pad -> 2-way bank alias only)
    __shared__ u16 Bs[256 * LSTR];
    const int tid = threadIdx.x;
    const int wave = tid >> 6;
    const int lane = tid & 63;
    const int mrow = lane & 15;
    const int quad = lane >> 4;

    constexpr int KC = KPAD / 8;            // 16B chunks per weight row
    for (int i = tid; i < 256 * KC; i += 512) {
        int r = i / KC, kc = i % KC;
        *(uint4*)&Bs[r * LSTR + kc * 8] =
            *(const uint4*)&Bt[(size_t)r * KPAD + kc * 8];
    }
    __syncthreads();

    for (long chunk = blockIdx.x; chunk * 256 < (long)M; chunk += gridDim.x) {
        const long mbase = chunk * 256 + wave * 32;
        long row[2];
#pragma unroll
        for (int t = 0; t < 2; ++t) {
            long r = mbase + t * 16 + mrow;
            if (r >= M) r = M - 1;
            row[t] = r;
        }

        f32x4v acc[2][16];
#pragma unroll
        for (int t = 0; t < 2; ++t)
#pragma unroll
            for (int j = 0; j < 16; ++j) acc[t][j] = (f32x4v){0.f, 0.f, 0.f, 0.f};

#pragma unroll 2
        for (int k0 = 0; k0 < KPAD; k0 += 32) {
            bf16x8v a_frag[2];
#pragma unroll
            for (int t = 0; t < 2; ++t)
                a_frag[t] = *(const bf16x8v*)&A[row[t] * KPAD + k0 + quad * 8];
#pragma unroll
            for (int jg = 0; jg < 4; ++jg) {
                bf16x8v b_frag[4];
#pragma unroll
                for (int j4 = 0; j4 < 4; ++j4)
                    b_frag[j4] = *(const bf16x8v*)&Bs[((jg * 4 + j4) * 16 + mrow) * LSTR + k0 + quad * 8];
#pragma unroll
                for (int t = 0; t < 2; ++t)
#pragma unroll
                    for (int j4 = 0; j4 < 4; ++j4)
                        acc[t][jg * 4 + j4] = __builtin_amdgcn_mfma_f32_16x16x32_bf16(
                            a_frag[t], b_frag[j4], acc[t][jg * 4 + j4], 0, 0, 0);
            }
        }

        // epilogue: C/D layout col=lane&15, row=quad*4+reg
#pragma unroll
        for (int t = 0; t < 2; ++t) {
#pragma unroll
            for (int r = 0; r < 4; ++r) {
                long grow = mbase + t * 16 + quad * 4 + r;
                if (grow < M) {
#pragma unroll
                    for (int j = 0; j < 16; ++j) {
                        int gcol = j * 16 + mrow;
                        size_t idx = (size_t)grow * 256 + gcol;
                        float v = acc[t][j][r];
                        if constexpr (MODE == 0) {
                            out0[idx] = f2bf(v);
                        } else {
                            float s = bf2f(inp[idx]) + v;
                            out0[idx] = f2bf(s > 0.f ? s : 0.f);
                        }
                    }
                }
            }
        }
    }
}

// ---------- streaming GEMM for the readout (split A, 64-col slices) ----------
template <int KPAD, int KSPLIT, int NT>
__global__ __launch_bounds__(256, 3)
void gemm_stream(const u16* __restrict__ A1, const u16* __restrict__ A2,
                 const u16* __restrict__ Bt, int M,
                 const float* __restrict__ bias, float* __restrict__ outf) {
    constexpr int LSTR = KPAD + 8;
    constexpr int NROWS = NT * 16;
    constexpr int K2 = KPAD - KSPLIT;
    __shared__ u16 Bs[NROWS * LSTR];
    const int tid = threadIdx.x;
    const int wave = tid >> 6;
    const int lane = tid & 63;
    const int mrow = lane & 15;
    const int quad = lane >> 4;
    const int nbase = blockIdx.y * NROWS;

    constexpr int KC = KPAD / 8;
    for (int i = tid; i < NROWS * KC; i += 256) {
        int r = i / KC, kc = i % KC;
        *(uint4*)&Bs[r * LSTR + kc * 8] =
            *(const uint4*)&Bt[(size_t)(nbase + r) * KPAD + kc * 8];
    }
    __syncthreads();

    for (long chunk = blockIdx.x; chunk * 256 < (long)M; chunk += gridDim.x) {
        const long mbase = chunk * 256 + wave * 64;
        long row[4];
#pragma unroll
        for (int t = 0; t < 4; ++t) {
            long r = mbase + t * 16 + mrow;
            if (r >= M) r = M - 1;
            row[t] = r;
        }

        f32x4v acc[4][NT];
#pragma unroll
        for (int t = 0; t < 4; ++t)
#pragma unroll
            for (int j = 0; j < NT; ++j) acc[t][j] = (f32x4v){0.f, 0.f, 0.f, 0.f};

#pragma unroll 2
        for (int k0 = 0; k0 < KSPLIT; k0 += 32) {
            bf16x8v a_frag[4], b_frag[NT];
#pragma unroll
            for (int t = 0; t < 4; ++t)
                a_frag[t] = *(const bf16x8v*)&A1[row[t] * KSPLIT + k0 + quad * 8];
#pragma unroll
            for (int j = 0; j < NT; ++j)
                b_frag[j] = *(const bf16x8v*)&Bs[(j * 16 + mrow) * LSTR + k0 + quad * 8];
#pragma unroll
            for (int t = 0; t < 4; ++t)
#pragma unroll
                for (int j = 0; j < NT; ++j)
                    acc[t][j] = __builtin_amdgcn_mfma_f32_16x16x32_bf16(
                        a_frag[t], b_frag[j], acc[t][j], 0, 0, 0);
        }
        if constexpr (K2 > 0) {
#pragma unroll 2
            for (int k0 = 0; k0 < K2; k0 += 32) {
                bf16x8v a_frag[4], b_frag[NT];
#pragma unroll
                for (int t = 0; t < 4; ++t)
                    a_frag[t] = *(const bf16x8v*)&A2[row[t] * K2 + k0 + quad * 8];
#pragma unroll
                for (int j = 0; j < NT; ++j)
                    b_frag[j] = *(const bf16x8v*)&Bs[(j * 16 + mrow) * LSTR + KSPLIT + k0 + quad * 8];
#pragma unroll
                for (int t = 0; t < 4; ++t)
#pragma unroll
                    for (int j = 0; j < NT; ++j)
                        acc[t][j] = __builtin_amdgcn_mfma_f32_16x16x32_bf16(
                            a_frag[t], b_frag[j], acc[t][j], 0, 0, 0);
            }
        }

#pragma unroll
        for (int t = 0; t < 4; ++t) {
#pragma unroll
            for (int r = 0; r < 4; ++r) {
                long grow = mbase + t * 16 + quad * 4 + r;
                if (grow < M) {
#pragma unroll
                    for (int j = 0; j < NT; ++j) {
                        int gcol = nbase + j * 16 + mrow;
                        float s = acc[t][j][r] + bias[gcol];
                        outf[(size_t)grow * 256 + gcol] = s > 0.f ? s : 0.f;
                    }
                }
            }
        }
    }
}

// ---------- per-molecule weighted mean (mol_ids sorted) ----------
__global__ __launch_bounds__(256)
void aggregate_kernel(const float* __restrict__ hid, const float* __restrict__ w_atoms,
                      const int* __restrict__ mol_ids, const float* __restrict__ deg,
                      float* __restrict__ out, int nAtoms) {
    int m = blockIdx.x;
    int t = threadIdx.x;
    int lo = 0, hi = nAtoms;
    while (lo < hi) { int mid = (lo + hi) >> 1; if (mol_ids[mid] < m) lo = mid + 1; else hi = mid; }
    int start = lo;
    lo = start; hi = nAtoms;
    while (lo < hi) { int mid = (lo + hi) >> 1; if (mol_ids[mid] < m + 1) lo = mid + 1; else hi = mid; }
    int end = lo;
    float acc = 0.f, wsum = 0.f;
    for (int a = start; a < end; ++a) {
        float w = w_atoms[a];
        wsum += w;
        acc += w * hid[(size_t)a * 256 + t];
    }
    float res = (wsum > 0.f) ? deg[m] * acc / wsum : 0.f;
    out[m * 256 + t] = res;
}

// ---------- launch ----------
extern "C" void kernel_launch(void* const* d_in, const int* in_sizes, int n_in,
                              void* d_out, int out_size, void* d_ws, size_t ws_size,
                              hipStream_t stream) {
    const float* f_atoms = (const float*)d_in[0];
    const float* f_bonds = (const float*)d_in[1];
    const float* w_atoms = (const float*)d_in[2];
    const float* w_bonds = (const float*)d_in[3];
    const float* W_i     = (const float*)d_in[4];
    const float* W_h     = (const float*)d_in[5];
    const float* W_o     = (const float*)d_in[6];
    const float* b_o     = (const float*)d_in[7];
    const float* deg     = (const float*)d_in[8];
    const int*   a2b     = (const int*)d_in[9];
    const int*   b2a     = (const int*)d_in[10];
    const int*   b2revb  = (const int*)d_in[11];
    const int*   mol_ids = (const int*)d_in[12];
    float* out = (float*)d_out;

    const int nB = 250000, nA = 100000, nM = 2000;

    // ws layout (bytes):
    //  P0 @ 0     : inp bf16 [250k][256] = 128 MB, becomes msgB in-place (GEMM2b epilogue)
    //  P1 @ 128M  : msgA bf16 [250k][256] = 128 MB, later fatoms_bf [100k][192]
    //  P2 @ 256M  : fbonds_bf [250k][192] -> mdir1/mdir2 [250k][256] -> hid fp32 [100k][256]
    //  P3 @ 384M  : amsg bf16 [100k][256] = 51.2 MB
    //  P4 @ 435.2M: Wt_i (98,304) | Wt_h (131,072) | Wt_o (229,376)
    char* ws = (char*)d_ws;
    u16* inp    = (u16*)(ws);
    u16* msgA   = (u16*)(ws + 128000000L);
    u16* buf2   = (u16*)(ws + 256000000L);
    u16* amsg   = (u16*)(ws + 384000000L);
    u16* wt_i   = (u16*)(ws + 435200000L);
    u16* wt_h   = (u16*)(ws + 435200000L + 98304L);
    u16* wt_o   = (u16*)(ws + 435200000L + 98304L + 131072L);
    u16* fatoms = msgA;
    float* hid  = (float*)buf2;

    if (ws_size < 435658752UL) return;

    dim3 b256(256), b512(512);
    pack_w<<<dim3((256 * 192 + 255) / 256), b256, 0, stream>>>(W_i, wt_i, 147, 192);
    pack_w<<<dim3((256 * 256 + 255) / 256), b256, 0, stream>>>(W_h, wt_h, 256, 256);
    pack_wo<<<dim3((256 * 448 + 255) / 256), b256, 0, stream>>>(W_o, wt_o);
    convert_fbonds<<<dim3(nB * 192 / 256), b256, 0, stream>>>(f_bonds, buf2, nB);

    // GEMM1: inp = fbonds_bf @ W_i^T   (A read once, full-N blocks)
    gemm_full<0, 192><<<dim3(256), b512, 0, stream>>>(buf2, wt_i, nB, nullptr, inp);

    // iteration 0 (msg == relu(inp) applied on the fly in gather/direct)
    gather16<true><<<dim3(nA / 8), b256, 0, stream>>>(inp, a2b, w_bonds, amsg, nA);
    direct16<true><<<dim3(nB / 8), b256, 0, stream>>>(amsg, inp, b2a, b2revb, buf2, nB);
    gemm_full<1, 256><<<dim3(256), b512, 0, stream>>>(buf2, wt_h, nB, inp, msgA);

    // iteration 1
    gather16<false><<<dim3(nA / 8), b256, 0, stream>>>(msgA, a2b, w_bonds, amsg, nA);
    direct16<false><<<dim3(nB / 8), b256, 0, stream>>>(amsg, msgA, b2a, b2revb, buf2, nB);
    gemm_full<1, 256><<<dim3(256), b512, 0, stream>>>(buf2, wt_h, nB, inp, inp);  // msgB in-place

    // final readout
    convert_fatoms<<<dim3(nA * 192 / 256), b256, 0, stream>>>(f_atoms, fatoms, nA);
    gather16<false><<<dim3(nA / 8), b256, 0, stream>>>(inp /*msgB*/, a2b, w_bonds, amsg, nA);
    gemm_stream<448, 256, 4><<<dim3(128, 4), b256, 0, stream>>>(
        amsg, fatoms, wt_o, nA, b_o, hid);

    aggregate_kernel<<<dim3(nM), b256, 0, stream>>>(hid, w_atoms, mol_ids, deg, out, nA);
}

// Round 6
// 852.263 us; speedup vs baseline: 1.5213x; 1.1807x over previous
//
#include <hip/hip_runtime.h>
#include <hip/hip_bf16.h>

typedef unsigned short u16;
typedef __bf16 bf16x8v __attribute__((ext_vector_type(8)));
typedef float f32x4v __attribute__((ext_vector_type(4)));
typedef float f32x4u __attribute__((ext_vector_type(4))) __attribute__((aligned(4)));

// ---------- bf16 helpers (RNE) ----------
__device__ __forceinline__ float bf2f(u16 u) {
    union { float f; unsigned int i; } c; c.i = ((unsigned int)u) << 16; return c.f;
}
__device__ __forceinline__ u16 f2bf(float f) {
    union { float f; unsigned int i; } c; c.f = f;
    unsigned int i = c.i;
    unsigned int lsb = (i >> 16) & 1u;
    i += 0x7fffu + lsb;
    return (u16)(i >> 16);
}
__device__ __forceinline__ float lo16(unsigned u) { return bf2f((u16)(u & 0xffff)); }
__device__ __forceinline__ float hi16(unsigned u) { return bf2f((u16)(u >> 16)); }
__device__ __forceinline__ unsigned pack2(float lo, float hi) {
    return (unsigned)f2bf(lo) | ((unsigned)f2bf(hi) << 16);
}

// load 8 fp32 from rowp[k..k+7] (guarded, zero-padded), convert to bf16x8 fragment
__device__ __forceinline__ bf16x8v load_cvt8(const float* __restrict__ rowp, int k, int kmax) {
    union { unsigned u[4]; bf16x8v v; } r;
#pragma unroll
    for (int g = 0; g < 2; ++g) {
        int kk = k + g * 4;
        float f0, f1, f2, f3;
        if (kk + 3 < kmax) {
            f32x4u q = *(const f32x4u*)(rowp + kk);
            f0 = q.x; f1 = q.y; f2 = q.z; f3 = q.w;
        } else {
            f0 = (kk + 0 < kmax) ? rowp[kk + 0] : 0.f;
            f1 = (kk + 1 < kmax) ? rowp[kk + 1] : 0.f;
            f2 = (kk + 2 < kmax) ? rowp[kk + 2] : 0.f;
            f3 = (kk + 3 < kmax) ? rowp[kk + 3] : 0.f;
        }
        r.u[g * 2]     = pack2(f0, f1);
        r.u[g * 2 + 1] = pack2(f2, f3);
    }
    return r.v;
}

// ---------- weight packing: Wt[n][k] = W[k][n], K padded with zeros ----------
__global__ void pack_w(const float* __restrict__ W, u16* __restrict__ Wt, int K, int Kpad) {
    int idx = blockIdx.x * 256 + threadIdx.x;
    if (idx >= 256 * Kpad) return;
    int n = idx / Kpad, k = idx % Kpad;
    float v = (k < K) ? W[k * 256 + n] : 0.f;
    Wt[idx] = f2bf(v);
}

// W_o packed for reordered concat: a_input = [a_message(256) | f_atoms(133) | pad(to 448)]
__global__ void pack_wo(const float* __restrict__ W_o, u16* __restrict__ Wt) {
    int idx = blockIdx.x * 256 + threadIdx.x;
    if (idx >= 256 * 448) return;
    int n = idx / 448, k = idx % 448;
    float v;
    if (k < 256)       v = W_o[(133 + k) * 256 + n];
    else if (k < 389)  v = W_o[(k - 256) * 256 + n];
    else               v = 0.f;
    Wt[idx] = f2bf(v);
}

// ---------- gather (16B/lane): amsg[a][h] = sum_j relu?(msg[a2b[a][j]][h]) * w_bonds[...] ----------
template <bool RELU>
__global__ __launch_bounds__(256)
void gather16(const u16* __restrict__ msg, const int* __restrict__ a2b,
              const float* __restrict__ w_bonds, u16* __restrict__ out, int nAtoms) {
    int t = threadIdx.x;
    int atom = blockIdx.x * 8 + (t >> 5);
    int co = (t & 31) * 8;
    if (atom >= nAtoms) return;
    float a[8] = {0.f, 0.f, 0.f, 0.f, 0.f, 0.f, 0.f, 0.f};
#pragma unroll
    for (int j = 0; j < 6; ++j) {
        int b = a2b[atom * 6 + j];
        float w = w_bonds[b];
        uint4 v = *(const uint4*)(msg + (size_t)b * 256 + co);
        unsigned p[4] = {v.x, v.y, v.z, v.w};
#pragma unroll
        for (int q = 0; q < 4; ++q) {
            float m0 = lo16(p[q]), m1 = hi16(p[q]);
            if (RELU) { m0 = fmaxf(m0, 0.f); m1 = fmaxf(m1, 0.f); }
            a[q * 2]     += w * m0;
            a[q * 2 + 1] += w * m1;
        }
    }
    uint4 o;
    o.x = pack2(a[0], a[1]); o.y = pack2(a[2], a[3]);
    o.z = pack2(a[4], a[5]); o.w = pack2(a[6], a[7]);
    *(uint4*)(out + (size_t)atom * 256 + co) = o;
}

// ---------- GEMM1: inp = f_bonds(fp32, stride 147) @ W_i^T, conversion fused into A-load ----------
// Full 256-col weight in LDS (one stage, one barrier). 512 thr / 8 waves, wave = 32 rows x 256 cols.
__global__ __launch_bounds__(512, 2)
void gemm_in(const float* __restrict__ A, const u16* __restrict__ Bt, int M,
             u16* __restrict__ out0) {
    constexpr int KPAD = 160, KMAX = 147, ASTR = 147;
    constexpr int LSTR = KPAD + 8;
    __shared__ u16 Bs[256 * LSTR];
    const int tid = threadIdx.x;
    const int wave = tid >> 6;
    const int lane = tid & 63;
    const int mrow = lane & 15;
    const int quad = lane >> 4;

    constexpr int KC = KPAD / 8;
    for (int i = tid; i < 256 * KC; i += 512) {
        int r = i / KC, kc = i % KC;
        *(uint4*)&Bs[r * LSTR + kc * 8] = *(const uint4*)&Bt[(size_t)r * KPAD + kc * 8];
    }
    __syncthreads();

    for (long chunk = blockIdx.x; chunk * 256 < (long)M; chunk += gridDim.x) {
        const long mbase = chunk * 256 + wave * 32;
        const float* rowp[2];
#pragma unroll
        for (int t = 0; t < 2; ++t) {
            long r = mbase + t * 16 + mrow;
            if (r >= M) r = M - 1;
            rowp[t] = A + r * ASTR;
        }

        f32x4v acc[2][16];
#pragma unroll
        for (int t = 0; t < 2; ++t)
#pragma unroll
            for (int j = 0; j < 16; ++j) acc[t][j] = (f32x4v){0.f, 0.f, 0.f, 0.f};

#pragma unroll 2
        for (int k0 = 0; k0 < KPAD; k0 += 32) {
            bf16x8v a_frag[2];
#pragma unroll
            for (int t = 0; t < 2; ++t)
                a_frag[t] = load_cvt8(rowp[t], k0 + quad * 8, KMAX);
#pragma unroll
            for (int jg = 0; jg < 4; ++jg) {
                bf16x8v b_frag[4];
#pragma unroll
                for (int j4 = 0; j4 < 4; ++j4)
                    b_frag[j4] = *(const bf16x8v*)&Bs[((jg * 4 + j4) * 16 + mrow) * LSTR + k0 + quad * 8];
#pragma unroll
                for (int t = 0; t < 2; ++t)
#pragma unroll
                    for (int j4 = 0; j4 < 4; ++j4)
                        acc[t][jg * 4 + j4] = __builtin_amdgcn_mfma_f32_16x16x32_bf16(
                            a_frag[t], b_frag[j4], acc[t][jg * 4 + j4], 0, 0, 0);
            }
        }

#pragma unroll
        for (int t = 0; t < 2; ++t)
#pragma unroll
            for (int r = 0; r < 4; ++r) {
                long grow = mbase + t * 16 + quad * 4 + r;
                if (grow < M)
#pragma unroll
                    for (int j = 0; j < 16; ++j)
                        out0[(size_t)grow * 256 + j * 16 + mrow] = f2bf(acc[t][j][r]);
            }
    }
}

// ---------- fused message-passing GEMM ----------
// msg_new[b][:] = relu( inp[b] + (amsg[b2a[b]] - relu?(msgsrc[b2revb[b]])) @ Wh^T )
// A-fragments gathered on the fly (each bond row read exactly once). Full-N, zero k-loop barriers.
template <bool RELUV>
__global__ __launch_bounds__(512, 2)
void gemm_mp(const u16* __restrict__ amsg, const u16* __restrict__ msgsrc,
             const int* __restrict__ b2a, const int* __restrict__ b2revb,
             const u16* __restrict__ Bt, int M,
             const u16* __restrict__ inp, u16* __restrict__ out0) {
    constexpr int KPAD = 256;
    constexpr int LSTR = KPAD + 8;
    __shared__ u16 Bs[256 * LSTR];
    const int tid = threadIdx.x;
    const int wave = tid >> 6;
    const int lane = tid & 63;
    const int mrow = lane & 15;
    const int quad = lane >> 4;

    constexpr int KC = KPAD / 8;
    for (int i = tid; i < 256 * KC; i += 512) {
        int r = i / KC, kc = i % KC;
        *(uint4*)&Bs[r * LSTR + kc * 8] = *(const uint4*)&Bt[(size_t)r * KPAD + kc * 8];
    }
    __syncthreads();

    for (long chunk = blockIdx.x; chunk * 256 < (long)M; chunk += gridDim.x) {
        const long mbase = chunk * 256 + wave * 32;
        size_t soff[2], roff[2];
#pragma unroll
        for (int t = 0; t < 2; ++t) {
            long b = mbase + t * 16 + mrow;
            if (b >= M) b = M - 1;
            soff[t] = (size_t)b2a[b] * 256 + quad * 8;
            roff[t] = (size_t)b2revb[b] * 256 + quad * 8;
        }

        f32x4v acc[2][16];
#pragma unroll
        for (int t = 0; t < 2; ++t)
#pragma unroll
            for (int j = 0; j < 16; ++j) acc[t][j] = (f32x4v){0.f, 0.f, 0.f, 0.f};

#pragma unroll 2
        for (int k0 = 0; k0 < KPAD; k0 += 32) {
            bf16x8v a_frag[2];
#pragma unroll
            for (int t = 0; t < 2; ++t) {
                uint4 va = *(const uint4*)&amsg[soff[t] + k0];
                uint4 vr = *(const uint4*)&msgsrc[roff[t] + k0];
                unsigned pa[4] = {va.x, va.y, va.z, va.w};
                unsigned pr[4] = {vr.x, vr.y, vr.z, vr.w};
                union { unsigned u[4]; bf16x8v v; } res;
#pragma unroll
                for (int p = 0; p < 4; ++p) {
                    float rl = lo16(pr[p]), rh = hi16(pr[p]);
                    if (RELUV) { rl = fmaxf(rl, 0.f); rh = fmaxf(rh, 0.f); }
                    res.u[p] = pack2(lo16(pa[p]) - rl, hi16(pa[p]) - rh);
                }
                a_frag[t] = res.v;
            }
#pragma unroll
            for (int jg = 0; jg < 4; ++jg) {
                bf16x8v b_frag[4];
#pragma unroll
                for (int j4 = 0; j4 < 4; ++j4)
                    b_frag[j4] = *(const bf16x8v*)&Bs[((jg * 4 + j4) * 16 + mrow) * LSTR + k0 + quad * 8];
#pragma unroll
                for (int t = 0; t < 2; ++t)
#pragma unroll
                    for (int j4 = 0; j4 < 4; ++j4)
                        acc[t][jg * 4 + j4] = __builtin_amdgcn_mfma_f32_16x16x32_bf16(
                            a_frag[t], b_frag[j4], acc[t][jg * 4 + j4], 0, 0, 0);
            }
        }

        // epilogue: msg_new = relu(inp + acc)   (out0 may alias inp: own-idx read-then-write only)
#pragma unroll
        for (int t = 0; t < 2; ++t)
#pragma unroll
            for (int r = 0; r < 4; ++r) {
                long grow = mbase + t * 16 + quad * 4 + r;
                if (grow < M)
#pragma unroll
                    for (int j = 0; j < 16; ++j) {
                        size_t idx = (size_t)grow * 256 + j * 16 + mrow;
                        float s = bf2f(inp[idx]) + acc[t][j][r];
                        out0[idx] = f2bf(s > 0.f ? s : 0.f);
                    }
            }
    }
}

// ---------- readout GEMM: hid = relu([amsg | f_atoms] @ Wo^T + b), f_atoms fp32 fused ----------
// 128-col slices (grid.y=2), 512 thr, wave = 32 rows x 128 cols.
__global__ __launch_bounds__(512, 2)
void gemm_ro(const u16* __restrict__ A1, const float* __restrict__ A2,
             const u16* __restrict__ Bt, int M,
             const float* __restrict__ bias, float* __restrict__ outf) {
    constexpr int KPAD = 448, KSPLIT = 256, K2 = 192, KMAX2 = 133;
    constexpr int LSTR = KPAD + 8;
    constexpr int NROWS = 128;
    __shared__ u16 Bs[NROWS * LSTR];
    const int tid = threadIdx.x;
    const int wave = tid >> 6;
    const int lane = tid & 63;
    const int mrow = lane & 15;
    const int quad = lane >> 4;
    const int nbase = blockIdx.y * NROWS;

    constexpr int KC = KPAD / 8;
    for (int i = tid; i < NROWS * KC; i += 512) {
        int r = i / KC, kc = i % KC;
        *(uint4*)&Bs[r * LSTR + kc * 8] =
            *(const uint4*)&Bt[(size_t)(nbase + r) * KPAD + kc * 8];
    }
    __syncthreads();

    for (long chunk = blockIdx.x; chunk * 256 < (long)M; chunk += gridDim.x) {
        const long mbase = chunk * 256 + wave * 32;
        long row[2];
#pragma unroll
        for (int t = 0; t < 2; ++t) {
            long r = mbase + t * 16 + mrow;
            if (r >= M) r = M - 1;
            row[t] = r;
        }

        f32x4v acc[2][8];
#pragma unroll
        for (int t = 0; t < 2; ++t)
#pragma unroll
            for (int j = 0; j < 8; ++j) acc[t][j] = (f32x4v){0.f, 0.f, 0.f, 0.f};

#pragma unroll 2
        for (int k0 = 0; k0 < KSPLIT; k0 += 32) {
            bf16x8v a_frag[2], b_frag[8];
#pragma unroll
            for (int t = 0; t < 2; ++t)
                a_frag[t] = *(const bf16x8v*)&A1[row[t] * KSPLIT + k0 + quad * 8];
#pragma unroll
            for (int j = 0; j < 8; ++j)
                b_frag[j] = *(const bf16x8v*)&Bs[(j * 16 + mrow) * LSTR + k0 + quad * 8];
#pragma unroll
            for (int t = 0; t < 2; ++t)
#pragma unroll
                for (int j = 0; j < 8; ++j)
                    acc[t][j] = __builtin_amdgcn_mfma_f32_16x16x32_bf16(
                        a_frag[t], b_frag[j], acc[t][j], 0, 0, 0);
        }
#pragma unroll 2
        for (int k0 = 0; k0 < K2; k0 += 32) {
            bf16x8v a_frag[2], b_frag[8];
#pragma unroll
            for (int t = 0; t < 2; ++t)
                a_frag[t] = load_cvt8(A2 + row[t] * KMAX2, k0 + quad * 8, KMAX2);
#pragma unroll
            for (int j = 0; j < 8; ++j)
                b_frag[j] = *(const bf16x8v*)&Bs[(j * 16 + mrow) * LSTR + KSPLIT + k0 + quad * 8];
#pragma unroll
            for (int t = 0; t < 2; ++t)
#pragma unroll
                for (int j = 0; j < 8; ++j)
                    acc[t][j] = __builtin_amdgcn_mfma_f32_16x16x32_bf16(
                        a_frag[t], b_frag[j], acc[t][j], 0, 0, 0);
        }

#pragma unroll
        for (int t = 0; t < 2; ++t)
#pragma unroll
            for (int r = 0; r < 4; ++r) {
                long grow = mbase + t * 16 + quad * 4 + r;
                if (grow < M)
#pragma unroll
                    for (int j = 0; j < 8; ++j) {
                        int gcol = nbase + j * 16 + mrow;
                        float s = acc[t][j][r] + bias[gcol];
                        outf[(size_t)grow * 256 + gcol] = s > 0.f ? s : 0.f;
                    }
            }
    }
}

// ---------- per-molecule weighted mean (mol_ids sorted) ----------
__global__ __launch_bounds__(256)
void aggregate_kernel(const float* __restrict__ hid, const float* __restrict__ w_atoms,
                      const int* __restrict__ mol_ids, const float* __restrict__ deg,
                      float* __restrict__ out, int nAtoms) {
    int m = blockIdx.x;
    int t = threadIdx.x;
    int lo = 0, hi = nAtoms;
    while (lo < hi) { int mid = (lo + hi) >> 1; if (mol_ids[mid] < m) lo = mid + 1; else hi = mid; }
    int start = lo;
    lo = start; hi = nAtoms;
    while (lo < hi) { int mid = (lo + hi) >> 1; if (mol_ids[mid] < m + 1) lo = mid + 1; else hi = mid; }
    int end = lo;
    float acc = 0.f, wsum = 0.f;
    for (int a = start; a < end; ++a) {
        float w = w_atoms[a];
        wsum += w;
        acc += w * hid[(size_t)a * 256 + t];
    }
    float res = (wsum > 0.f) ? deg[m] * acc / wsum : 0.f;
    out[m * 256 + t] = res;
}

// ---------- launch ----------
extern "C" void kernel_launch(void* const* d_in, const int* in_sizes, int n_in,
                              void* d_out, int out_size, void* d_ws, size_t ws_size,
                              hipStream_t stream) {
    const float* f_atoms = (const float*)d_in[0];
    const float* f_bonds = (const float*)d_in[1];
    const float* w_atoms = (const float*)d_in[2];
    const float* w_bonds = (const float*)d_in[3];
    const float* W_i     = (const float*)d_in[4];
    const float* W_h     = (const float*)d_in[5];
    const float* W_o     = (const float*)d_in[6];
    const float* b_o     = (const float*)d_in[7];
    const float* deg     = (const float*)d_in[8];
    const int*   a2b     = (const int*)d_in[9];
    const int*   b2a     = (const int*)d_in[10];
    const int*   b2revb  = (const int*)d_in[11];
    const int*   mol_ids = (const int*)d_in[12];
    float* out = (float*)d_out;

    const int nB = 250000, nA = 100000, nM = 2000;

    // ws layout (bytes):
    //  P0 @ 0     : inp bf16 [250k][256] = 128 MB (becomes msgB in-place after iter-1 GEMM)
    //  P1 @ 128M  : msgA bf16 [250k][256] = 128 MB
    //  P2 @ 256M  : hid fp32 [100k][256] = 102.4 MB
    //  P3 @ 384M  : amsg bf16 [100k][256] = 51.2 MB
    //  P4 @ 435.2M: Wt_i (81,920) | Wt_h (131,072) | Wt_o (229,376)
    char* ws = (char*)d_ws;
    u16* inp    = (u16*)(ws);
    u16* msgA   = (u16*)(ws + 128000000L);
    float* hid  = (float*)(ws + 256000000L);
    u16* amsg   = (u16*)(ws + 384000000L);
    u16* wt_i   = (u16*)(ws + 435200000L);
    u16* wt_h   = (u16*)(ws + 435200000L + 81920L);
    u16* wt_o   = (u16*)(ws + 435200000L + 81920L + 131072L);

    if (ws_size < 435642368UL) return;

    dim3 b256(256), b512(512);
    pack_w<<<dim3((256 * 160 + 255) / 256), b256, 0, stream>>>(W_i, wt_i, 147, 160);
    pack_w<<<dim3((256 * 256 + 255) / 256), b256, 0, stream>>>(W_h, wt_h, 256, 256);
    pack_wo<<<dim3((256 * 448 + 255) / 256), b256, 0, stream>>>(W_o, wt_o);

    // GEMM1: inp = f_bonds @ W_i^T (fp32 A, conversion fused)
    gemm_in<<<dim3(977), b512, 0, stream>>>(f_bonds, wt_i, nB, inp);

    // iteration 0 (msg == relu(inp) on the fly everywhere)
    gather16<true><<<dim3(nA / 8), b256, 0, stream>>>(inp, a2b, w_bonds, amsg, nA);
    gemm_mp<true><<<dim3(977), b512, 0, stream>>>(
        amsg, inp, b2a, b2revb, wt_h, nB, inp, msgA);

    // iteration 1
    gather16<false><<<dim3(nA / 8), b256, 0, stream>>>(msgA, a2b, w_bonds, amsg, nA);
    gemm_mp<false><<<dim3(977), b512, 0, stream>>>(
        amsg, msgA, b2a, b2revb, wt_h, nB, inp, inp);   // msgB in-place over inp

    // final readout
    gather16<false><<<dim3(nA / 8), b256, 0, stream>>>(inp /*msgB*/, a2b, w_bonds, amsg, nA);
    gemm_ro<<<dim3(391, 2), b512, 0, stream>>>(amsg, f_atoms, wt_o, nA, b_o, hid);

    aggregate_kernel<<<dim3(nM), b256, 0, stream>>>(hid, w_atoms, mol_ids, deg, out, nA);
}